// Round 18
// baseline (310.591 us; speedup 1.0000x reference)
//
#include <hip/hip_runtime.h>
#include <hip/hip_fp16.h>

typedef __attribute__((ext_vector_type(8))) short bf16x8;
typedef __attribute__((ext_vector_type(4))) float f32x4;

__device__ __forceinline__ unsigned short f2bf(float f) {  // RNE
  unsigned u = __float_as_uint(f);
  u += 0x7FFFu + ((u >> 16) & 1u);
  return (unsigned short)(u >> 16);
}
__device__ __forceinline__ float bflo(unsigned u) { return __uint_as_float(u << 16); }
__device__ __forceinline__ float bfhi(unsigned u) { return __uint_as_float(u & 0xFFFF0000u); }
__device__ __forceinline__ float bf1(unsigned short h) { return __uint_as_float(((unsigned)h) << 16); }
__device__ __forceinline__ float unpackw(unsigned pk) {
  return __half2float(__ushort_as_half((unsigned short)(pk >> 16)));
}

// ---------------- MFMA bf16 GEMM body (R13 form: 64 rows/block) ----------------
template <int CO, bool AF32>
__device__ __forceinline__ void gemm_body(const void* __restrict__ Aptr,
                                          const float* __restrict__ W,
                                          unsigned short* __restrict__ Y, int N,
                                          int bid, int tid, unsigned short* Wl) {
  constexpr int K = 128;
  constexpr int SP = K + 8;  // padded LDS row stride (shorts)
  for (int i = tid; i < K * CO; i += 256) {
    int k = i / CO, n = i % CO;
    Wl[n * SP + k] = f2bf(W[i]);
  }
  __syncthreads();

  const int lane = tid & 63;
  const int quad = lane >> 4, l16 = lane & 15;
  const int mbase = bid * 64 + (tid >> 6) * 16;
  const int arow = min(mbase + l16, N - 1);

  bf16x8 afrag[4];
  if constexpr (AF32) {
    const float* A = (const float*)Aptr + (size_t)arow * K;
#pragma unroll
    for (int ks = 0; ks < 4; ks++) {
      const float4* p = (const float4*)(A + ks * 32 + quad * 8);
      float4 f0 = p[0], f1 = p[1];
      afrag[ks] = (bf16x8){(short)f2bf(f0.x), (short)f2bf(f0.y), (short)f2bf(f0.z), (short)f2bf(f0.w),
                           (short)f2bf(f1.x), (short)f2bf(f1.y), (short)f2bf(f1.z), (short)f2bf(f1.w)};
    }
  } else {
    const unsigned short* A = (const unsigned short*)Aptr + (size_t)arow * K;
#pragma unroll
    for (int ks = 0; ks < 4; ks++) afrag[ks] = *(const bf16x8*)(A + ks * 32 + quad * 8);
  }

#pragma unroll
  for (int ct = 0; ct < CO / 16; ct++) {
    f32x4 acc = {0.0f, 0.0f, 0.0f, 0.0f};
#pragma unroll
    for (int ks = 0; ks < 4; ks++) {
      bf16x8 b = *(const bf16x8*)(&Wl[(ct * 16 + l16) * SP + ks * 32 + quad * 8]);
      acc = __builtin_amdgcn_mfma_f32_16x16x32_bf16(afrag[ks], b, acc, 0, 0, 0);
    }
#pragma unroll
    for (int reg = 0; reg < 4; reg++) {
      int node = mbase + quad * 4 + reg;
      if (node < N) Y[(size_t)node * CO + ct * 16 + l16] = f2bf(acc[reg]);
    }
  }
}

// ---- mega1: GEMM1 | histogram + direct bucket scatter | batch boundaries --------
// (R13/R16 exact) Bucket layout: colsrc[d*64 + r] = src, r = atomic rank (cap 64).
__global__ __launch_bounds__(256) void k_mega1(const float* __restrict__ x,
                                               const float* __restrict__ W1,
                                               unsigned short* __restrict__ xw1b, int N,
                                               const int* __restrict__ src,
                                               const int* __restrict__ dst,
                                               int* __restrict__ cnt,
                                               unsigned short* __restrict__ colsrc, int E,
                                               const int* __restrict__ batch,
                                               int* __restrict__ firstIdx,
                                               int gM, int gE4) {
  __shared__ unsigned short Wl[128 * 136];
  const int bid = blockIdx.x, tid = threadIdx.x;
  if (bid < gM) {
    gemm_body<128, true>(x, W1, xw1b, N, bid, tid, Wl);
  } else if (bid < gM + gE4) {
    int e0 = (bid - gM) * 1024 + tid * 4;
    if (e0 + 3 < E) {
      int4 d4 = *(const int4*)(dst + e0);
      int4 s4 = *(const int4*)(src + e0);
      int r;
      r = atomicAdd(&cnt[d4.x], 1); if (r < 64) colsrc[(d4.x << 6) + r] = (unsigned short)s4.x;
      r = atomicAdd(&cnt[d4.y], 1); if (r < 64) colsrc[(d4.y << 6) + r] = (unsigned short)s4.y;
      r = atomicAdd(&cnt[d4.z], 1); if (r < 64) colsrc[(d4.z << 6) + r] = (unsigned short)s4.z;
      r = atomicAdd(&cnt[d4.w], 1); if (r < 64) colsrc[(d4.w << 6) + r] = (unsigned short)s4.w;
    } else {
      for (int e = e0; e < E; e++) {
        int d = dst[e];
        int r = atomicAdd(&cnt[d], 1);
        if (r < 64) colsrc[(d << 6) + r] = (unsigned short)src[e];
      }
    }
  } else {
    int n = (bid - gM - gE4) * 256 + tid;
    if (n < N) {
      int b = batch[n];
      if (n == 0 || batch[n - 1] != b) firstIdx[b] = n + 1;  // first occurrence, +1-encoded
    }
  }
}

// ---- mega2: layer-1 aggregate (R16 body) | build C (edges) | build C (self) -----
// C factorization: pooled[g] = sum_u Ct[u][g] * h1[u];
// Ct[src*64 + batch[dst]] += w_e, Ct[v*64 + batch[v]] += dv^2.
__global__ __launch_bounds__(256) void k_mega2(const unsigned short* __restrict__ xwb,
                                               const int* __restrict__ cnt,
                                               const unsigned short* __restrict__ colsrc,
                                               const float* __restrict__ bias,
                                               unsigned short* __restrict__ out, int N,
                                               const int* __restrict__ src,
                                               const int* __restrict__ dst,
                                               const int* __restrict__ batch,
                                               float* __restrict__ Ct, int E,
                                               int gA, int gE4) {
  const int bid = blockIdx.x, tid = threadIdx.x;
  if (bid < gA) {
    // -------- layer-1 aggregate: one vertex per 16-lane group (R16 exact) --------
    const int lane = tid & 63;
    const int gl = lane & 15;   // lane within group (16B feature slice)
    const int grp = lane >> 4;  // group within wave (0..3)
    const int wv = tid >> 6;
    const int v = bid * 16 + wv * 4 + grp;
    const int vc = min(v, N - 1);

    const int c = cnt[vc];
    const int jc = (v < N) ? min(c, 64) : 0;
    const float dv = rsqrtf((float)(c + 1));

    float acc[8];
    {
      const float d2 = dv * dv;
      uint4 s = *(const uint4*)((const char*)xwb + (((size_t)vc << 8) | (gl << 4)));
      acc[0] = d2 * bflo(s.x); acc[1] = d2 * bfhi(s.x);
      acc[2] = d2 * bflo(s.y); acc[3] = d2 * bfhi(s.y);
      acc[4] = d2 * bflo(s.z); acc[5] = d2 * bfhi(s.z);
      acc[6] = d2 * bflo(s.w); acc[7] = d2 * bfhi(s.w);
    }

    const int gbase = grp << 4;
    for (int base = 0; __any(base < jc); base += 16) {
      unsigned pk0 = 0u;  // (s=0, w=0) pad
      if (base + gl < jc) {
        int s = colsrc[(vc << 6) + base + gl];
        float ws = rsqrtf((float)(cnt[s] + 1)) * dv;
        pk0 = (unsigned)s | ((unsigned)__half_as_ushort(__float2half_rn(ws)) << 16);
      }
      int mv = jc - base;
      mv = mv < 0 ? 0 : (mv > 16 ? 16 : mv);
      int mm = max(mv, __shfl_xor(mv, 16, 64));
      mm = max(mm, __shfl_xor(mm, 32, 64));
      const int rp = (mm + 7) & ~7;  // 8 or 16
      for (int t = 0; t < rp; t += 8) {
        uint4 rbuf[8];
        float wbuf[8];
#pragma unroll
        for (int r = 0; r < 8; r++) {
          unsigned pk = (unsigned)__shfl((int)pk0, gbase + t + r, 64);
          wbuf[r] = unpackw(pk);
          rbuf[r] = *(const uint4*)((const char*)xwb + (((pk & 0xFFFFu) << 8) | (gl << 4)));
        }
#pragma unroll
        for (int r = 0; r < 8; r++) {
          const float w = wbuf[r];
          const uint4 rr = rbuf[r];
          acc[0] += w * bflo(rr.x); acc[1] += w * bfhi(rr.x);
          acc[2] += w * bflo(rr.y); acc[3] += w * bfhi(rr.y);
          acc[4] += w * bflo(rr.z); acc[5] += w * bfhi(rr.z);
          acc[6] += w * bflo(rr.w); acc[7] += w * bfhi(rr.w);
        }
      }
    }

    if (v < N) {
      float4 b0 = ((const float4*)bias)[gl * 2];
      float4 b1 = ((const float4*)bias)[gl * 2 + 1];
      float a0 = fmaxf(acc[0] + b0.x, 0.f), a1 = fmaxf(acc[1] + b0.y, 0.f);
      float a2 = fmaxf(acc[2] + b0.z, 0.f), a3 = fmaxf(acc[3] + b0.w, 0.f);
      float a4 = fmaxf(acc[4] + b1.x, 0.f), a5 = fmaxf(acc[5] + b1.y, 0.f);
      float a6 = fmaxf(acc[6] + b1.z, 0.f), a7 = fmaxf(acc[7] + b1.w, 0.f);
      uint4 st;
      st.x = (unsigned)f2bf(a0) | ((unsigned)f2bf(a1) << 16);
      st.y = (unsigned)f2bf(a2) | ((unsigned)f2bf(a3) << 16);
      st.z = (unsigned)f2bf(a4) | ((unsigned)f2bf(a5) << 16);
      st.w = (unsigned)f2bf(a6) | ((unsigned)f2bf(a7) << 16);
      *(uint4*)((char*)out + (((size_t)v << 8) | (gl << 4))) = st;
    }
  } else if (bid < gA + gE4) {
    // -------- build C from edges: Ct[s*64 + batch[d]] += dinv[s]*dinv[d] ---------
    int e0 = (bid - gA) * 1024 + tid * 4;
    if (e0 + 3 < E) {
      int4 s4 = *(const int4*)(src + e0);
      int4 d4 = *(const int4*)(dst + e0);
      {
        float w = rsqrtf((float)(cnt[s4.x] + 1)) * rsqrtf((float)(cnt[d4.x] + 1));
        atomicAdd(&Ct[(size_t)s4.x * 64 + batch[d4.x]], w);
      }
      {
        float w = rsqrtf((float)(cnt[s4.y] + 1)) * rsqrtf((float)(cnt[d4.y] + 1));
        atomicAdd(&Ct[(size_t)s4.y * 64 + batch[d4.y]], w);
      }
      {
        float w = rsqrtf((float)(cnt[s4.z] + 1)) * rsqrtf((float)(cnt[d4.z] + 1));
        atomicAdd(&Ct[(size_t)s4.z * 64 + batch[d4.z]], w);
      }
      {
        float w = rsqrtf((float)(cnt[s4.w] + 1)) * rsqrtf((float)(cnt[d4.w] + 1));
        atomicAdd(&Ct[(size_t)s4.w * 64 + batch[d4.w]], w);
      }
    } else {
      for (int e = e0; e < E; e++) {
        int s = src[e], d = dst[e];
        float w = rsqrtf((float)(cnt[s] + 1)) * rsqrtf((float)(cnt[d] + 1));
        atomicAdd(&Ct[(size_t)s * 64 + batch[d]], w);
      }
    }
  } else {
    // -------- build C self-loops: Ct[v*64 + batch[v]] += 1/(cnt[v]+1) ------------
    int v = (bid - gA - gE4) * 256 + tid;
    if (v < N) atomicAdd(&Ct[(size_t)v * 64 + batch[v]], 1.0f / (float)(cnt[v] + 1));
  }
}

// ---- dense pooled GEMM: part[b] = Ct[k0:k1]^T @ h1[k0:k1]  (64 x 128 partials) ---
// Thread (gq=tid&15, fs=tid>>4): 4 graphs x 8 feats. Streaming, atomic-free.
__global__ __launch_bounds__(256) void k_poolgemm(const unsigned short* __restrict__ h1b,
                                                  const float* __restrict__ Ct,
                                                  float* __restrict__ part, int N, int NB) {
  const int bid = blockIdx.x, tid = threadIdx.x;
  const int gq = tid & 15;   // graph quad: g = gq*4 .. gq*4+3
  const int fs = tid >> 4;   // feature set: f = fs*8 .. fs*8+7
  const int chunk = (N + NB - 1) / NB;
  const int k0 = bid * chunk;
  const int k1 = min(k0 + chunk, N);

  float acc[4][8];
#pragma unroll
  for (int gi = 0; gi < 4; gi++)
#pragma unroll
    for (int fi = 0; fi < 8; fi++) acc[gi][fi] = 0.0f;

  for (int k = k0; k < k1; k++) {
    float4 c4 = *(const float4*)(Ct + (size_t)k * 64 + gq * 4);
    bf16x8 h8 = *(const bf16x8*)(h1b + (size_t)k * 128 + fs * 8);
#pragma unroll
    for (int fi = 0; fi < 8; fi++) {
      float hv = bf1((unsigned short)h8[fi]);
      acc[0][fi] += c4.x * hv;
      acc[1][fi] += c4.y * hv;
      acc[2][fi] += c4.z * hv;
      acc[3][fi] += c4.w * hv;
    }
  }

  float* pb = part + (size_t)bid * 8192;
#pragma unroll
  for (int gi = 0; gi < 4; gi++)
#pragma unroll
    for (int fi = 0; fi < 8; fi++)
      pb[(gq * 4 + gi) * 128 + fs * 8 + fi] = acc[gi][fi];
}

// ---- final: pooled[g] = sum_b part[b][g]; out[g] = (pooled/c_g) @ W2 + b2 -------
__global__ void k_wout(const float* __restrict__ part, const int* __restrict__ firstIdx,
                       const float* __restrict__ W2, const float* __restrict__ b2,
                       float* __restrict__ out, int N, int NB) {
  __shared__ float denom[64];
  __shared__ float pooled[128];
  __shared__ float red[256];
  const int tid = threadIdx.x;
  const int g = blockIdx.x;
  if (tid < 64) {
    int raw = firstIdx[tid];
    int fi = (raw > 0) ? raw - 1 : 0x7FFFFFFF;
    int m = fi;
#pragma unroll
    for (int d = 1; d < 64; d <<= 1) {
      int t = __shfl_down(m, d, 64);
      if (tid + d < 64) m = min(m, t);
    }
    int nxtm = __shfl_down(m, 1, 64);          // min first over graphs > tid
    int nxt = (tid == 63) ? N : min(nxtm, N);
    int c = (fi == 0x7FFFFFFF) ? 0 : (nxt - fi);
    denom[tid] = fmaxf((float)c, 1.0f);
  }
  if (tid < 128) {
    float s0 = 0.f, s1 = 0.f;
    for (int b = 0; b + 1 < NB; b += 2) {
      s0 += part[(size_t)b * 8192 + g * 128 + tid];
      s1 += part[(size_t)(b + 1) * 8192 + g * 128 + tid];
    }
    if (NB & 1) s0 += part[(size_t)(NB - 1) * 8192 + g * 128 + tid];
    pooled[tid] = s0 + s1;
  }
  __syncthreads();
  const int j = tid & 63, kc = tid >> 6;
  float p = 0.0f;
#pragma unroll 8
  for (int k = kc * 32; k < kc * 32 + 32; k++)
    p += pooled[k] * W2[k * 64 + j];
  red[tid] = p;
  __syncthreads();
  if (tid < 64) {
    float t = red[tid] + red[tid + 64] + red[tid + 128] + red[tid + 192];
    out[g * 64 + tid] = t / denom[g] + b2[tid];
  }
}

// ---------------- launch ----------------

extern "C" void kernel_launch(void* const* d_in, const int* in_sizes, int n_in,
                              void* d_out, int out_size, void* d_ws, size_t ws_size,
                              hipStream_t stream) {
  const float* x     = (const float*)d_in[0];
  const int*   ei    = (const int*)d_in[1];
  const int*   batch = (const int*)d_in[2];
  const float* W1    = (const float*)d_in[3];
  const float* b1    = (const float*)d_in[4];
  const float* W2    = (const float*)d_in[5];
  const float* b2    = (const float*)d_in[6];

  const int N = in_sizes[2];       // 50000  (< 65536: src fits in 16 bits)
  const int E = in_sizes[1] / 2;   // 800000
  const int* src  = ei;
  const int* dstv = ei + E;

  const int NB = 256;  // poolgemm partial blocks

  // workspace layout
  unsigned short* xw1b = (unsigned short*)d_ws;      // N*128 bf16
  unsigned short* h1b  = xw1b + (size_t)N * 128;     // N*128 bf16
  // zero region (single memset): cnt[N], firstIdx[64], Ct[N*64]
  int*   cnt     = (int*)(h1b + (size_t)N * 128);
  int*   firstIdx= cnt + N;
  float* Ct      = (float*)(firstIdx + 64);          // N*64 f32
  // non-zeroed scratch
  float* part    = Ct + (size_t)N * 64;              // NB*8192 f32 (fully written)
  unsigned short* colsrc = (unsigned short*)(part + (size_t)NB * 8192);  // N*64 ushort
  float* outp    = (float*)d_out;                    // 64*64

  hipMemsetAsync(cnt, 0, ((size_t)N + 64 + (size_t)N * 64) * sizeof(int), stream);

  const int gM  = (N + 63) / 64;      // 782  (64 rows/block)
  const int gE4 = (E + 1023) / 1024;  // 782  (4 edges/thread)
  const int gN  = (N + 255) / 256;    // 196
  const int gA1 = (N + 15) / 16;      // 3125 (16 vertices/block)

  // GEMM1 + histogram/bucket-scatter + batch boundaries in one launch
  k_mega1<<<gM + gE4 + gN, 256, 0, stream>>>(x, W1, xw1b, N, src, dstv, cnt,
                                             colsrc, E, batch, firstIdx, gM, gE4);

  // layer-1 aggregate (+bias+relu) -> h1  ||  build C (edges + self-loops)
  k_mega2<<<gA1 + gE4 + gN, 256, 0, stream>>>(xw1b, cnt, colsrc, b1, h1b, N,
                                              src, dstv, batch, Ct, E, gA1, gE4);

  // dense pooled GEMM: part = Ct^T @ h1 (per-block partials, atomic-free)
  k_poolgemm<<<NB, 256, 0, stream>>>(h1b, Ct, part, N, NB);

  // reduce partials, divide by counts, apply W2 + b2
  k_wout<<<64, 256, 0, stream>>>(part, firstIdx, W2, b2, outp, N, NB);
}

// Round 19
// 189.514 us; speedup vs baseline: 1.6389x; 1.6389x over previous
//
#include <hip/hip_runtime.h>
#include <hip/hip_fp16.h>

typedef __attribute__((ext_vector_type(8))) short bf16x8;
typedef __attribute__((ext_vector_type(4))) float f32x4;

__device__ __forceinline__ unsigned short f2bf(float f) {  // RNE
  unsigned u = __float_as_uint(f);
  u += 0x7FFFu + ((u >> 16) & 1u);
  return (unsigned short)(u >> 16);
}
__device__ __forceinline__ float bflo(unsigned u) { return __uint_as_float(u << 16); }
__device__ __forceinline__ float bfhi(unsigned u) { return __uint_as_float(u & 0xFFFF0000u); }
__device__ __forceinline__ float unpackw(unsigned pk) {
  return __half2float(__ushort_as_half((unsigned short)(pk >> 16)));
}

// ---------------- MFMA bf16 GEMM body (R13 form: 64 rows/block) ----------------
template <int CO, bool AF32>
__device__ __forceinline__ void gemm_body(const void* __restrict__ Aptr,
                                          const float* __restrict__ W,
                                          unsigned short* __restrict__ Y, int N,
                                          int bid, int tid, unsigned short* Wl) {
  constexpr int K = 128;
  constexpr int SP = K + 8;  // padded LDS row stride (shorts)
  for (int i = tid; i < K * CO; i += 256) {
    int k = i / CO, n = i % CO;
    Wl[n * SP + k] = f2bf(W[i]);
  }
  __syncthreads();

  const int lane = tid & 63;
  const int quad = lane >> 4, l16 = lane & 15;
  const int mbase = bid * 64 + (tid >> 6) * 16;
  const int arow = min(mbase + l16, N - 1);

  bf16x8 afrag[4];
  if constexpr (AF32) {
    const float* A = (const float*)Aptr + (size_t)arow * K;
#pragma unroll
    for (int ks = 0; ks < 4; ks++) {
      const float4* p = (const float4*)(A + ks * 32 + quad * 8);
      float4 f0 = p[0], f1 = p[1];
      afrag[ks] = (bf16x8){(short)f2bf(f0.x), (short)f2bf(f0.y), (short)f2bf(f0.z), (short)f2bf(f0.w),
                           (short)f2bf(f1.x), (short)f2bf(f1.y), (short)f2bf(f1.z), (short)f2bf(f1.w)};
    }
  } else {
    const unsigned short* A = (const unsigned short*)Aptr + (size_t)arow * K;
#pragma unroll
    for (int ks = 0; ks < 4; ks++) afrag[ks] = *(const bf16x8*)(A + ks * 32 + quad * 8);
  }

#pragma unroll
  for (int ct = 0; ct < CO / 16; ct++) {
    f32x4 acc = {0.0f, 0.0f, 0.0f, 0.0f};
#pragma unroll
    for (int ks = 0; ks < 4; ks++) {
      bf16x8 b = *(const bf16x8*)(&Wl[(ct * 16 + l16) * SP + ks * 32 + quad * 8]);
      acc = __builtin_amdgcn_mfma_f32_16x16x32_bf16(afrag[ks], b, acc, 0, 0, 0);
    }
#pragma unroll
    for (int reg = 0; reg < 4; reg++) {
      int node = mbase + quad * 4 + reg;
      if (node < N) Y[(size_t)node * CO + ct * 16 + l16] = f2bf(acc[reg]);
    }
  }
}

// ---- mega1: GEMM1 | histogram + direct bucket scatter | batch boundaries --------
// (R13 exact) Bucket layout: colsrc[d*64 + r] = src, r = atomic rank (cap 64).
__global__ __launch_bounds__(256) void k_mega1(const float* __restrict__ x,
                                               const float* __restrict__ W1,
                                               unsigned short* __restrict__ xw1b, int N,
                                               const int* __restrict__ src,
                                               const int* __restrict__ dst,
                                               int* __restrict__ cnt,
                                               unsigned short* __restrict__ colsrc, int E,
                                               const int* __restrict__ batch,
                                               int* __restrict__ firstIdx,
                                               int gM, int gE4) {
  __shared__ unsigned short Wl[128 * 136];
  const int bid = blockIdx.x, tid = threadIdx.x;
  if (bid < gM) {
    gemm_body<128, true>(x, W1, xw1b, N, bid, tid, Wl);
  } else if (bid < gM + gE4) {
    int e0 = (bid - gM) * 1024 + tid * 4;
    if (e0 + 3 < E) {
      int4 d4 = *(const int4*)(dst + e0);
      int4 s4 = *(const int4*)(src + e0);
      int r;
      r = atomicAdd(&cnt[d4.x], 1); if (r < 64) colsrc[(d4.x << 6) + r] = (unsigned short)s4.x;
      r = atomicAdd(&cnt[d4.y], 1); if (r < 64) colsrc[(d4.y << 6) + r] = (unsigned short)s4.y;
      r = atomicAdd(&cnt[d4.z], 1); if (r < 64) colsrc[(d4.z << 6) + r] = (unsigned short)s4.z;
      r = atomicAdd(&cnt[d4.w], 1); if (r < 64) colsrc[(d4.w << 6) + r] = (unsigned short)s4.w;
    } else {
      for (int e = e0; e < E; e++) {
        int d = dst[e];
        int r = atomicAdd(&cnt[d], 1);
        if (r < 64) colsrc[(d << 6) + r] = (unsigned short)src[e];
      }
    }
  } else {
    int n = (bid - gM - gE4) * 256 + tid;
    if (n < N) {
      int b = batch[n];
      if (n == 0 || batch[n - 1] != b) firstIdx[b] = n + 1;  // first occurrence, +1-encoded
    }
  }
}

// ---- layer-1 aggregate: one vertex per 16-lane group, on-the-fly weights --------
__global__ __launch_bounds__(256) void k_agg128(const unsigned short* __restrict__ xwb,
                                                const int* __restrict__ cnt,
                                                const unsigned short* __restrict__ colsrc,
                                                const float* __restrict__ bias,
                                                unsigned short* __restrict__ out, int N) {
  const int tid = threadIdx.x;
  const int lane = tid & 63;
  const int gl = lane & 15;   // lane within group (16B feature slice)
  const int grp = lane >> 4;  // group within wave (0..3)
  const int wv = tid >> 6;
  const int v = blockIdx.x * 16 + wv * 4 + grp;
  const int vc = min(v, N - 1);

  const int c = cnt[vc];
  const int jc = (v < N) ? min(c, 64) : 0;
  const float dv = rsqrtf((float)(c + 1));

  // self-loop (each lane owns a distinct 16B slice)
  float acc[8];
  {
    const float d2 = dv * dv;
    uint4 s = *(const uint4*)((const char*)xwb + (((size_t)vc << 8) | (gl << 4)));
    acc[0] = d2 * bflo(s.x); acc[1] = d2 * bfhi(s.x);
    acc[2] = d2 * bflo(s.y); acc[3] = d2 * bfhi(s.y);
    acc[4] = d2 * bflo(s.z); acc[5] = d2 * bfhi(s.z);
    acc[6] = d2 * bflo(s.w); acc[7] = d2 * bfhi(s.w);
  }

  const int gbase = grp << 4;
  for (int base = 0; __any(base < jc); base += 16) {
    unsigned pk0 = 0u;  // (s=0, w=0) pad
    if (base + gl < jc) {
      int s = colsrc[(vc << 6) + base + gl];
      float ws = rsqrtf((float)(cnt[s] + 1)) * dv;
      pk0 = (unsigned)s | ((unsigned)__half_as_ushort(__float2half_rn(ws)) << 16);
    }
    int mv = jc - base;
    mv = mv < 0 ? 0 : (mv > 16 ? 16 : mv);
    int mm = max(mv, __shfl_xor(mv, 16, 64));
    mm = max(mm, __shfl_xor(mm, 32, 64));
    const int rp = (mm + 7) & ~7;  // 8 or 16
    for (int t = 0; t < rp; t += 8) {
      uint4 rbuf[8];
      float wbuf[8];
#pragma unroll
      for (int r = 0; r < 8; r++) {
        unsigned pk = (unsigned)__shfl((int)pk0, gbase + t + r, 64);
        wbuf[r] = unpackw(pk);
        rbuf[r] = *(const uint4*)((const char*)xwb + (((pk & 0xFFFFu) << 8) | (gl << 4)));
      }
#pragma unroll
      for (int r = 0; r < 8; r++) {
        const float w = wbuf[r];
        const uint4 rr = rbuf[r];
        acc[0] += w * bflo(rr.x); acc[1] += w * bfhi(rr.x);
        acc[2] += w * bflo(rr.y); acc[3] += w * bfhi(rr.y);
        acc[4] += w * bflo(rr.z); acc[5] += w * bfhi(rr.z);
        acc[6] += w * bflo(rr.w); acc[7] += w * bfhi(rr.w);
      }
    }
  }

  if (v < N) {
    float4 b0 = ((const float4*)bias)[gl * 2];
    float4 b1 = ((const float4*)bias)[gl * 2 + 1];
    float a0 = fmaxf(acc[0] + b0.x, 0.f), a1 = fmaxf(acc[1] + b0.y, 0.f);
    float a2 = fmaxf(acc[2] + b0.z, 0.f), a3 = fmaxf(acc[3] + b0.w, 0.f);
    float a4 = fmaxf(acc[4] + b1.x, 0.f), a5 = fmaxf(acc[5] + b1.y, 0.f);
    float a6 = fmaxf(acc[6] + b1.z, 0.f), a7 = fmaxf(acc[7] + b1.w, 0.f);
    uint4 st;
    st.x = (unsigned)f2bf(a0) | ((unsigned)f2bf(a1) << 16);
    st.y = (unsigned)f2bf(a2) | ((unsigned)f2bf(a3) << 16);
    st.z = (unsigned)f2bf(a4) | ((unsigned)f2bf(a5) << 16);
    st.w = (unsigned)f2bf(a6) | ((unsigned)f2bf(a7) << 16);
    *(uint4*)((char*)out + (((size_t)v << 8) | (gl << 4))) = st;
  }
}

// ---- layer-2 aggregate of h1 pooled per graph (W2 deferred past pooling) --------
// Pooling commutes with W2: pool(Ahat (h1 W2)) = (pool(Ahat h1)) W2.
__global__ __launch_bounds__(256) void k_aggpool2(const unsigned short* __restrict__ h1b,
                                                  const int* __restrict__ cnt,
                                                  const unsigned short* __restrict__ colsrc,
                                                  const int* __restrict__ batch,
                                                  float* __restrict__ stage, int N) {
  __shared__ float sAcc[4][128];
  const int tid = threadIdx.x;
  const int lane = tid & 63;
  const int gl = lane & 15;   // lane within group (16B feature slice)
  const int grp = lane >> 4;  // group within wave (0..3)
  const int wv = tid >> 6;
  const int v = blockIdx.x * 16 + wv * 4 + grp;
  const int vc = min(v, N - 1);

  const int c = cnt[vc];
  const int jc = (v < N) ? min(c, 64) : 0;
  const float dv = rsqrtf((float)(c + 1));

  float acc[8];
  {
    const float d2 = (v < N) ? dv * dv : 0.0f;
    uint4 s = *(const uint4*)((const char*)h1b + (((size_t)vc << 8) | (gl << 4)));
    acc[0] = d2 * bflo(s.x); acc[1] = d2 * bfhi(s.x);
    acc[2] = d2 * bflo(s.y); acc[3] = d2 * bfhi(s.y);
    acc[4] = d2 * bflo(s.z); acc[5] = d2 * bfhi(s.z);
    acc[6] = d2 * bflo(s.w); acc[7] = d2 * bfhi(s.w);
  }

  const int gbase = grp << 4;
  for (int base = 0; __any(base < jc); base += 16) {
    unsigned pk0 = 0u;  // (s=0, w=0) pad
    if (base + gl < jc) {
      int s = colsrc[(vc << 6) + base + gl];
      float ws = rsqrtf((float)(cnt[s] + 1)) * dv;
      pk0 = (unsigned)s | ((unsigned)__half_as_ushort(__float2half_rn(ws)) << 16);
    }
    int mv = jc - base;
    mv = mv < 0 ? 0 : (mv > 16 ? 16 : mv);
    int mm = max(mv, __shfl_xor(mv, 16, 64));
    mm = max(mm, __shfl_xor(mm, 32, 64));
    const int rp = (mm + 7) & ~7;  // 8 or 16
    for (int t = 0; t < rp; t += 8) {
      uint4 rbuf[8];
      float wbuf[8];
#pragma unroll
      for (int r = 0; r < 8; r++) {
        unsigned pk = (unsigned)__shfl((int)pk0, gbase + t + r, 64);
        wbuf[r] = unpackw(pk);
        rbuf[r] = *(const uint4*)((const char*)h1b + (((pk & 0xFFFFu) << 8) | (gl << 4)));
      }
#pragma unroll
      for (int r = 0; r < 8; r++) {
        const float w = wbuf[r];
        const uint4 rr = rbuf[r];
        acc[0] += w * bflo(rr.x); acc[1] += w * bfhi(rr.x);
        acc[2] += w * bflo(rr.y); acc[3] += w * bfhi(rr.y);
        acc[4] += w * bflo(rr.z); acc[5] += w * bfhi(rr.z);
        acc[6] += w * bflo(rr.w); acc[7] += w * bfhi(rr.w);
      }
    }
  }

  const int v0 = blockIdx.x * 16;
  const bool uniform = (v0 + 15 < N) && (batch[v0] == batch[v0 + 15]);
  if (uniform) {
    // sum across the 4 groups (feature slice gl preserved)
#pragma unroll
    for (int d = 16; d < 64; d <<= 1)
#pragma unroll
      for (int k = 0; k < 8; k++) acc[k] += __shfl_xor(acc[k], d, 64);
    if (grp == 0) {
#pragma unroll
      for (int k = 0; k < 8; k++) sAcc[wv][gl * 8 + k] = acc[k];
    }
    __syncthreads();
    if (wv == 0) {
      const int g = batch[v0];
      float t0 = sAcc[0][lane] + sAcc[1][lane] + sAcc[2][lane] + sAcc[3][lane];
      float t1 = sAcc[0][lane + 64] + sAcc[1][lane + 64] + sAcc[2][lane + 64] + sAcc[3][lane + 64];
      atomicAdd(&stage[g * 128 + lane], t0);
      atomicAdd(&stage[g * 128 + lane + 64], t1);
    }
  } else if (v < N) {
    const int b = batch[vc];
#pragma unroll
    for (int k = 0; k < 8; k++) atomicAdd(&stage[b * 128 + gl * 8 + k], acc[k]);
  }
}

// ---- final: out[g] = (stage[g] / c_g) @ W2 + b2  (64 blocks, one per graph) -----
__global__ void k_wout(const float* __restrict__ stage, const int* __restrict__ firstIdx,
                       const float* __restrict__ W2, const float* __restrict__ b2,
                       float* __restrict__ out, int N) {
  __shared__ float denom[64];
  __shared__ float red[256];
  const int tid = threadIdx.x;
  const int g = blockIdx.x;
  if (tid < 64) {
    int raw = firstIdx[tid];
    int fi = (raw > 0) ? raw - 1 : 0x7FFFFFFF;
    int m = fi;
#pragma unroll
    for (int d = 1; d < 64; d <<= 1) {
      int t = __shfl_down(m, d, 64);
      if (tid + d < 64) m = min(m, t);
    }
    int nxtm = __shfl_down(m, 1, 64);          // min first over graphs > tid
    int nxt = (tid == 63) ? N : min(nxtm, N);
    int c = (fi == 0x7FFFFFFF) ? 0 : (nxt - fi);
    denom[tid] = fmaxf((float)c, 1.0f);
  }
  __syncthreads();
  const int j = tid & 63, kc = tid >> 6;
  float p = 0.0f;
#pragma unroll 8
  for (int k = kc * 32; k < kc * 32 + 32; k++)
    p += stage[g * 128 + k] * W2[k * 64 + j];
  red[tid] = p;
  __syncthreads();
  if (tid < 64) {
    float t = red[tid] + red[tid + 64] + red[tid + 128] + red[tid + 192];
    out[g * 64 + tid] = t / denom[g] + b2[tid];
  }
}

// ---------------- launch ----------------

extern "C" void kernel_launch(void* const* d_in, const int* in_sizes, int n_in,
                              void* d_out, int out_size, void* d_ws, size_t ws_size,
                              hipStream_t stream) {
  const float* x     = (const float*)d_in[0];
  const int*   ei    = (const int*)d_in[1];
  const int*   batch = (const int*)d_in[2];
  const float* W1    = (const float*)d_in[3];
  const float* b1    = (const float*)d_in[4];
  const float* W2    = (const float*)d_in[5];
  const float* b2    = (const float*)d_in[6];

  const int N = in_sizes[2];       // 50000  (< 65536: src fits in 16 bits)
  const int E = in_sizes[1] / 2;   // 800000
  const int* src  = ei;
  const int* dstv = ei + E;

  // workspace layout
  unsigned short* xw1b = (unsigned short*)d_ws;      // N*128 bf16
  unsigned short* h1b  = xw1b + (size_t)N * 128;     // N*128 bf16
  // zero region (single memset): cnt[N], firstIdx[64], stage[64*128]
  int*   cnt     = (int*)(h1b + (size_t)N * 128);
  int*   firstIdx= cnt + N;
  float* stage   = (float*)(firstIdx + 64);          // 64*128 f32
  // non-zeroed scratch
  unsigned short* colsrc = (unsigned short*)(stage + 64 * 128);  // N*64 ushort buckets
  float* outp    = (float*)d_out;                    // 64*64

  hipMemsetAsync(cnt, 0, (size_t)(N + 64 + 64 * 128) * sizeof(int), stream);

  const int gM  = (N + 63) / 64;      // 782  (64 rows/block)
  const int gE4 = (E + 1023) / 1024;  // 782  (4 edges/thread histogram)
  const int gN  = (N + 255) / 256;    // 196
  const int gA1 = (N + 15) / 16;      // 3125 (16 vertices/block)

  // GEMM1 + histogram/bucket-scatter + batch boundaries in one launch
  k_mega1<<<gM + gE4 + gN, 256, 0, stream>>>(x, W1, xw1b, N, src, dstv, cnt,
                                             colsrc, E, batch, firstIdx, gM, gE4);

  // layer 1 aggregate (+bias+relu) -> h1
  k_agg128<<<gA1, 256, 0, stream>>>(xw1b, cnt, colsrc, b1, h1b, N);

  // layer 2 aggregate of h1, pooled per graph (W2 deferred past pooling)
  k_aggpool2<<<gA1, 256, 0, stream>>>(h1b, cnt, colsrc, batch, stage, N);

  // tiny final GEMM: (stage / c_g) @ W2 + b2
  k_wout<<<64, 256, 0, stream>>>(stage, firstIdx, W2, b2, outp, N);
}